// Round 10
// baseline (568.542 us; speedup 1.0000x reference)
//
#include <hip/hip_runtime.h>
#include <stdint.h>
#include <stddef.h>

typedef __bf16 bf16_t;
typedef bf16_t bf16x4 __attribute__((ext_vector_type(4)));
typedef bf16_t bf16x8 __attribute__((ext_vector_type(8)));
typedef float  f32x4  __attribute__((ext_vector_type(4)));
typedef _Float16 f16_t;
typedef f16_t f16x2 __attribute__((ext_vector_type(2)));
typedef f16_t f16x4 __attribute__((ext_vector_type(4)));
typedef __fp16 fp16x2_raw __attribute__((ext_vector_type(2)));   // cvt_pkrtz native type

__device__ __forceinline__ f16x2 pkrtz(float a, float b) {
    fp16x2_raw r = __builtin_amdgcn_cvt_pkrtz(a, b);
    union { fp16x2_raw r; f16x2 h; } u;
    u.r = r;
    return u.h;
}

#define MFMA_BF16_K32(a, b, c) __builtin_amdgcn_mfma_f32_16x16x32_bf16(a, b, c, 0, 0, 0)
#define MFMA_F16_K16(a, b, c)  __builtin_amdgcn_mfma_f32_16x16x16f16(a, b, c, 0, 0, 0)

// ---------------------------------------------------------------- helpers
__device__ __forceinline__ void gload_lds16(const void* g, void* l) {
    __builtin_amdgcn_global_load_lds(
        (const __attribute__((address_space(1))) void*)g,
        (__attribute__((address_space(3))) void*)l,
        16, 0, 0);
}

// ---------------------------------------------------------------- fused fp32 -> bf16 casts
#define NX 1572864           // x  float4 count
#define NWA 442368           // Wa float4 count
#define NWP 147456           // Wp float4 count
__global__ void cvt_all(const float* __restrict__ x, const float* __restrict__ Wa,
                        const float* __restrict__ Wp, bf16_t* __restrict__ xb,
                        bf16_t* __restrict__ Wab, bf16_t* __restrict__ Wpb) {
    int i = blockIdx.x * blockDim.x + threadIdx.x;
    const float4* src; bf16_t* dst; int j;
    if (i < NX)            { src = (const float4*)x;  dst = xb;  j = i; }
    else if (i < NX + NWA) { src = (const float4*)Wa; dst = Wab; j = i - NX; }
    else                   { src = (const float4*)Wp; dst = Wpb; j = i - NX - NWA; }
    float4 f = src[j];
    bf16x4 o = { (bf16_t)f.x, (bf16_t)f.y, (bf16_t)f.z, (bf16_t)f.w };
    ((bf16x4*)dst)[j] = o;
}

// ---------------------------------------------------------------- GEMM main loop
template <int KDIM>
__device__ __forceinline__ void gemm_mainloop(
    const bf16_t* __restrict__ A, const bf16_t* __restrict__ Bt,
    bf16_t* As, bf16_t* Bs, int m0, int n0, int wave, int lane, f32x4 acc[4][4])
{
    const int quad = lane >> 4, l15 = lane & 15;
    const int wm = ((wave >> 1) << 6), wn = ((wave & 1) << 6);

    const int srow = (wave << 4) + (lane >> 2);                 // 0..63
    const int sw   = (((lane & 3) ^ ((srow >> 1) & 3)) << 3);   // swizzled elem offset
    const bf16_t* gA = A  + (size_t)(m0 + srow) * KDIM + sw;
    const bf16_t* gB = Bt + (size_t)(n0 + srow) * KDIM + sw;
    bf16_t* lA0 = As + wave * 512;
    bf16_t* lA1 = As + 2048 + wave * 512;
    bf16_t* lB0 = Bs + wave * 512;
    bf16_t* lB1 = Bs + 2048 + wave * 512;

    const int xorv = ((quad ^ ((l15 >> 1) & 3)) << 3);

    for (int k0 = 0; k0 < KDIM; k0 += 32) {
        __syncthreads();
        gload_lds16(gA + k0,                       lA0);
        gload_lds16(gA + (size_t)64 * KDIM + k0,   lA1);
        gload_lds16(gB + k0,                       lB0);
        gload_lds16(gB + (size_t)64 * KDIM + k0,   lB1);
        __syncthreads();

        bf16x8 af[4], bfr[4];
#pragma unroll
        for (int t = 0; t < 4; t++) {
            af[t]  = *(const bf16x8*)(As + (wm + t * 16 + l15) * 32 + xorv);
            bfr[t] = *(const bf16x8*)(Bs + (wn + t * 16 + l15) * 32 + xorv);
        }
#pragma unroll
        for (int mt = 0; mt < 4; mt++)
#pragma unroll
            for (int nt = 0; nt < 4; nt++)
                acc[mt][nt] = MFMA_BF16_K32(af[mt], bfr[nt], acc[mt][nt]);
    }
}

// ---------------------------------------------------------------- QKV projection
__global__ __launch_bounds__(256) void gemm_qkv(
    const bf16_t* __restrict__ A,   // [8192,768]
    const bf16_t* __restrict__ Bt,  // [2304,768]
    const float* __restrict__ bias, // [2304]
    bf16_t* __restrict__ qo, bf16_t* __restrict__ ko, f16_t* __restrict__ vo)
{
    __shared__ bf16_t As[128 * 32];
    __shared__ bf16_t Bs[128 * 32];
    const int tid = threadIdx.x, wave = tid >> 6, lane = tid & 63;
    const int quad = lane >> 4, l15 = lane & 15;
    const int m0 = blockIdx.y * 128, n0 = blockIdx.x * 128;
    f32x4 acc[4][4] = {};
    gemm_mainloop<768>(A, Bt, As, Bs, m0, n0, wave, lane, acc);

    const int wm = ((wave >> 1) << 6), wn = ((wave & 1) << 6);
#pragma unroll
    for (int nt = 0; nt < 4; nt++) {
        const int cc = n0 + wn + nt * 16 + l15;     // 0..2303
        const float bia = bias[cc];
        const int which = cc / 768;
        const int rem = cc - which * 768;
        const int h = rem >> 6, d = rem & 63;
        if (which < 2) {
            bf16_t* dst = (which == 0) ? qo : ko;
#pragma unroll
            for (int mt = 0; mt < 4; mt++) {
#pragma unroll
                for (int r = 0; r < 4; r++) {
                    const int row = m0 + wm + mt * 16 + quad * 4 + r; // 0..8191
                    const int b = row >> 12, t = row & 4095;
                    dst[((size_t)(b * 12 + h) * 4096 + t) * 64 + d] =
                        (bf16_t)(acc[mt][nt][r] + bia);
                }
            }
        } else {
            // V transposed f16: vo[((b*12+h)*64 + d)*4096 + t]
#pragma unroll
            for (int mt = 0; mt < 4; mt++) {
                const int row0 = m0 + wm + mt * 16 + quad * 4;
                const int b = row0 >> 12, t0 = row0 & 4095;
                f16x4 ov = { (f16_t)(acc[mt][nt][0] + bia),
                             (f16_t)(acc[mt][nt][1] + bia),
                             (f16_t)(acc[mt][nt][2] + bia),
                             (f16_t)(acc[mt][nt][3] + bia) };
                *(f16x4*)(vo + ((size_t)(b * 12 + h) * 64 + d) * 4096 + t0) = ov;
            }
        }
    }
}

// ---------------------------------------------------------------- output projection
__global__ __launch_bounds__(256) void gemm_proj(
    const bf16_t* __restrict__ A,   // y bf16 [8192,768]
    const bf16_t* __restrict__ Bt,  // W_proj bf16 [768,768]
    const float* __restrict__ bias, // [768]
    float* __restrict__ out)        // [8192,768] fp32
{
    __shared__ bf16_t As[128 * 32];
    __shared__ bf16_t Bs[128 * 32];
    const int tid = threadIdx.x, wave = tid >> 6, lane = tid & 63;
    const int quad = lane >> 4, l15 = lane & 15;
    const int m0 = blockIdx.y * 128, n0 = blockIdx.x * 128;
    f32x4 acc[4][4] = {};
    gemm_mainloop<768>(A, Bt, As, Bs, m0, n0, wave, lane, acc);

    const int wm = ((wave >> 1) << 6), wn = ((wave & 1) << 6);
#pragma unroll
    for (int nt = 0; nt < 4; nt++) {
        const int cc = n0 + wn + nt * 16 + l15;
        const float bia = bias[cc];
#pragma unroll
        for (int mt = 0; mt < 4; mt++) {
#pragma unroll
            for (int r = 0; r < 4; r++) {
                const int row = m0 + wm + mt * 16 + quad * 4 + r;
                out[(size_t)row * 768 + cc] = acc[mt][nt][r] + bia;
            }
        }
    }
}

// ---------------------------------------------------------------- flash attention v9b
// r7 skeleton (LDS staging + key-split, the 184us baseline) with a VALU diet:
//   exp2f -> __builtin_amdgcn_exp2f (bare v_exp_f32, no ocml wrapper)
//   f32->f16 via cvt_pkrtz (2 elems/instr), psum via v_dot2_f32_f16 (2/instr)
//   pointer-bump staging addresses; launch_bounds(256,4) (36.8KB LDS fits 4)
// Theory: VALUBusy~63% is a true per-SIMD busy fraction -> issue-bound.
#define QSCALE 0.1803368801f   // log2(e)/8
__global__ __launch_bounds__(256, 4) void attn_fwd(
    const bf16_t* __restrict__ qg, const bf16_t* __restrict__ kg,
    const f16_t* __restrict__ vtg, bf16_t* __restrict__ y) // y [B,T,C] bf16
{
    __shared__ __align__(16) char smem[36608];
    bf16_t* Ks0 = (bf16_t*)(smem);              // 8KB [key][dim] swizzled
    bf16_t* Ks1 = (bf16_t*)(smem + 8192);
    f16_t*  Vt0 = (f16_t*)(smem + 16384);       // 8KB [dim][key] swizzled
    f16_t*  Vt1 = (f16_t*)(smem + 24576);
    float*  RedA = (float*)(smem);              // epilogue overlays (stride 68)
    float*  RedB = (float*)(smem + 17408);
    float*  Psr  = (float*)(smem + 34816);      // [4][64]
    float*  PsT  = (float*)(smem + 35840);      // [64]

    const int tid = threadIdx.x, wave = tid >> 6, lane = tid & 63;
    const int quad = lane >> 4, l15 = lane & 15;

    const int blk = blockIdx.x;            // 0..1535
    const int xcd = blk & 7;
    const int idx = blk >> 3;              // 0..191
    const int hl  = idx % 3;
    const int qt  = idx / 3;               // 0..63
    const int bh  = xcd * 3 + hl;          // 0..23
    const int b = bh / 12, h = bh - b * 12;
    const size_t base = (size_t)bh * 4096 * 64;

    // Q fragments for all 4 qrow-chunks (B-operand: n=l15, k=quad*8+j), *log2e/8
    bf16x8 qf[4][2];
#pragma unroll
    for (int qc = 0; qc < 4; qc++) {
        const int qrow = qt * 64 + qc * 16 + l15;
        qf[qc][0] = *(const bf16x8*)(qg + base + (size_t)qrow * 64 + quad * 8);
        qf[qc][1] = *(const bf16x8*)(qg + base + (size_t)qrow * 64 + 32 + quad * 8);
#pragma unroll
        for (int j = 0; j < 8; j++) {
            qf[qc][0][j] = (bf16_t)((float)qf[qc][0][j] * QSCALE);
            qf[qc][1][j] = (bf16_t)((float)qf[qc][1][j] * QSCALE);
        }
    }

    f32x4 O[4][4] = {};      // O^T partial: [dt][qc]; dim=dt*16+quad*4+r, qrow=qc*16+l15
    float psum[4] = {};      // per-lane partial row sums (qrow = qc*16+l15)
    const f16x2 one2 = { (f16_t)1.0f, (f16_t)1.0f };

    // staging: 8 lanes per 128B row, 16B chunks XOR-swizzled on row&7
    const int srow8 = tid >> 3;                  // 0..31 (+32 for i=1)
    const int sc8   = (tid & 7) ^ (srow8 & 7);
    const int l8 = l15 & 7;
    const int w16 = wave << 4;
    const int ksoff = (quad ^ l8) << 3;                          // K frag slot (elems)
    const int vslot = ((wave << 1) | (quad >> 1)) ^ l8;          // V frag 16B slot
    const int q0off = (quad & 1) * 8;

    auto stage = [&](const bf16_t* kp, const f16_t* vp, bf16_t* Kd, f16_t* Vd) {
#pragma unroll
        for (int i = 0; i < 2; i++) {
            gload_lds16(kp + (i * 32 + srow8) * 64 + sc8 * 8,           Kd + (i * 256 + tid) * 8);
            gload_lds16(vp + (size_t)(i * 32 + srow8) * 4096 + sc8 * 8, Vd + (i * 256 + tid) * 8);
        }
    };

    auto compute = [&](const bf16_t* ks, const f16_t* vs) {
        // ---- S^T (wave's 16 keys x 64 qrows): 2 LDS reads feed 8 MFMAs
        const bf16_t* kr = ks + (w16 + l15) * 64;
        bf16x8 kf0 = *(const bf16x8*)(kr + ksoff);
        bf16x8 kf1 = *(const bf16x8*)(kr + (ksoff ^ 32));
        f32x4 sc[4];
#pragma unroll
        for (int qc = 0; qc < 4; qc++) {
            f32x4 s = {};
            s = MFMA_BF16_K32(kf0, qf[qc][0], s);
            s = MFMA_BF16_K32(kf1, qf[qc][1], s);
            sc[qc] = s;
        }
        // ---- P = exp2(S^T): bare v_exp_f32 + packed f16 cvt + dot2 row-sums
        f16x4 pf[4];
#pragma unroll
        for (int qc = 0; qc < 4; qc++) {
            float e0 = __builtin_amdgcn_exp2f(sc[qc][0]);
            float e1 = __builtin_amdgcn_exp2f(sc[qc][1]);
            float e2 = __builtin_amdgcn_exp2f(sc[qc][2]);
            float e3 = __builtin_amdgcn_exp2f(sc[qc][3]);
            f16x2 lo = pkrtz(e0, e1);
            f16x2 hi = pkrtz(e2, e3);
            psum[qc] = __builtin_amdgcn_fdot2(lo, one2, psum[qc], false);
            psum[qc] = __builtin_amdgcn_fdot2(hi, one2, psum[qc], false);
            f16x4 p;
            *(f16x2*)&p = lo;
            *(((f16x2*)&p) + 1) = hi;
            pf[qc] = p;
        }
        // ---- O^T += V^T P : 4 LDS b64 reads feed 16 MFMAs
#pragma unroll
        for (int dt = 0; dt < 4; dt++) {
            const char* vr = (const char*)(vs + (dt * 16 + l15) * 64);
            f16x4 vf = *(const f16x4*)(vr + vslot * 16 + q0off);
#pragma unroll
            for (int qc = 0; qc < 4; qc++)
                O[dt][qc] = MFMA_F16_K16(vf, pf[qc], O[dt][qc]);
        }
    };

    const bf16_t* kp = kg + base;    // +4096 elems (8KB) per 64-key tile
    const f16_t*  vp = vtg + base;   // +64 elems per tile
    stage(kp, vp, Ks0, Vt0); kp += 4096; vp += 64;
    for (int kt = 0; kt < 64; kt += 2) {
        __syncthreads();                 // buf0 loads drained; buf1 readers done
        stage(kp, vp, Ks1, Vt1); kp += 4096; vp += 64;
        compute(Ks0, Vt0);
        __syncthreads();
        if (kt + 2 < 64) { stage(kp, vp, Ks0, Vt0); kp += 4096; vp += 64; }
        compute(Ks1, Vt1);
    }

    // ================= epilogue: reduce O & psum across the 4 key-split waves
#pragma unroll
    for (int qc = 0; qc < 4; qc++) {
        psum[qc] += __shfl_xor(psum[qc], 16, 64);
        psum[qc] += __shfl_xor(psum[qc], 32, 64);
    }
    __syncthreads();   // K-loop LDS quiesced; overlay safe
    if (wave == 2) {
#pragma unroll
        for (int dt = 0; dt < 4; dt++)
#pragma unroll
            for (int qc = 0; qc < 4; qc++)
                *(f32x4*)(RedA + (qc * 16 + l15) * 68 + dt * 16 + quad * 4) = O[dt][qc];
    } else if (wave == 3) {
#pragma unroll
        for (int dt = 0; dt < 4; dt++)
#pragma unroll
            for (int qc = 0; qc < 4; qc++)
                *(f32x4*)(RedB + (qc * 16 + l15) * 68 + dt * 16 + quad * 4) = O[dt][qc];
    }
    if (quad == 0) {
#pragma unroll
        for (int qc = 0; qc < 4; qc++) Psr[wave * 64 + qc * 16 + l15] = psum[qc];
    }
    __syncthreads();   // S2
    if (wave == 0) {
#pragma unroll
        for (int dt = 0; dt < 4; dt++)
#pragma unroll
            for (int qc = 0; qc < 4; qc++)
                O[dt][qc] += *(const f32x4*)(RedA + (qc * 16 + l15) * 68 + dt * 16 + quad * 4);
    } else if (wave == 1) {
#pragma unroll
        for (int dt = 0; dt < 4; dt++)
#pragma unroll
            for (int qc = 0; qc < 4; qc++)
                O[dt][qc] += *(const f32x4*)(RedB + (qc * 16 + l15) * 68 + dt * 16 + quad * 4);
    }
    __syncthreads();   // S3
    if (wave == 1) {
#pragma unroll
        for (int dt = 0; dt < 4; dt++)
#pragma unroll
            for (int qc = 0; qc < 4; qc++)
                *(f32x4*)(RedA + (qc * 16 + l15) * 68 + dt * 16 + quad * 4) = O[dt][qc];
    } else if (wave == 3) {
        PsT[lane] = Psr[lane] + Psr[64 + lane] + Psr[128 + lane] + Psr[192 + lane];
    }
    __syncthreads();   // S4
    if (wave == 0) {
#pragma unroll
        for (int qc = 0; qc < 4; qc++) {
            const float rcp = 1.0f / PsT[qc * 16 + l15];
            const int t = qt * 64 + qc * 16 + l15;
            bf16_t* yr = y + ((size_t)b * 4096 + t) * 768 + h * 64 + quad * 4;
#pragma unroll
            for (int dt = 0; dt < 4; dt++) {
                f32x4 o4 = O[dt][qc] +
                    *(const f32x4*)(RedA + (qc * 16 + l15) * 68 + dt * 16 + quad * 4);
                bf16x4 ov = { (bf16_t)(o4[0] * rcp), (bf16_t)(o4[1] * rcp),
                              (bf16_t)(o4[2] * rcp), (bf16_t)(o4[3] * rcp) };
                *(bf16x4*)(yr + dt * 16) = ov;
            }
        }
    }
}

// ---------------------------------------------------------------- launch
extern "C" void kernel_launch(void* const* d_in, const int* in_sizes, int n_in,
                              void* d_out, int out_size, void* d_ws, size_t ws_size,
                              hipStream_t stream) {
    const float* x  = (const float*)d_in[0]; // [2,4096,768]
    const float* Wa = (const float*)d_in[1]; // [2304,768]
    const float* ba = (const float*)d_in[2]; // [2304]
    const float* Wp = (const float*)d_in[3]; // [768,768]
    const float* bp = (const float*)d_in[4]; // [768]
    float* out = (float*)d_out;              // [2,4096,768]

    char* ws = (char*)d_ws;
    bf16_t* xb  = (bf16_t*)(ws);                 //  6291456 elts
    bf16_t* Wab = (bf16_t*)(ws + 12582912);      //  1769472
    bf16_t* Wpb = (bf16_t*)(ws + 16121856);      //   589824
    bf16_t* qb  = (bf16_t*)(ws + 17301504);      //  [B,H,T,D] bf16
    bf16_t* kb  = (bf16_t*)(ws + 29884416);      //  [B,H,T,D] bf16
    f16_t*  vtb = (f16_t*)(ws + 42467328);       //  [B,H,D,T] f16 (transposed)
    bf16_t* yb  = (bf16_t*)(ws + 55050240);      //  [B,T,C] bf16

    cvt_all<<<8448, 256, 0, stream>>>(x, Wa, Wp, xb, Wab, Wpb);
    gemm_qkv <<<dim3(18, 64), 256, 0, stream>>>(xb, Wab, ba, qb, kb, vtb);
    attn_fwd <<<1536, 256, 0, stream>>>(qb, kb, vtb, yb);
    gemm_proj<<<dim3( 6, 64), 256, 0, stream>>>(yb, Wpb, bp, out);
}

// Round 11
// 277.663 us; speedup vs baseline: 2.0476x; 2.0476x over previous
//
#include <hip/hip_runtime.h>
#include <stdint.h>
#include <stddef.h>

typedef __bf16 bf16_t;
typedef bf16_t bf16x4 __attribute__((ext_vector_type(4)));
typedef bf16_t bf16x8 __attribute__((ext_vector_type(8)));
typedef float  f32x4  __attribute__((ext_vector_type(4)));
typedef _Float16 f16_t;
typedef f16_t f16x2 __attribute__((ext_vector_type(2)));
typedef f16_t f16x4 __attribute__((ext_vector_type(4)));
typedef __fp16 fp16x2_raw __attribute__((ext_vector_type(2)));   // cvt_pkrtz native type

__device__ __forceinline__ f16x2 pkrtz(float a, float b) {
    fp16x2_raw r = __builtin_amdgcn_cvt_pkrtz(a, b);
    union { fp16x2_raw r; f16x2 h; } u;
    u.r = r;
    return u.h;
}

#define MFMA_BF16_K32(a, b, c) __builtin_amdgcn_mfma_f32_16x16x32_bf16(a, b, c, 0, 0, 0)
#define MFMA_F16_K16(a, b, c)  __builtin_amdgcn_mfma_f32_16x16x16f16(a, b, c, 0, 0, 0)

// ---------------------------------------------------------------- helpers
__device__ __forceinline__ void gload_lds16(const void* g, void* l) {
    __builtin_amdgcn_global_load_lds(
        (const __attribute__((address_space(1))) void*)g,
        (__attribute__((address_space(3))) void*)l,
        16, 0, 0);
}

// ---------------------------------------------------------------- fused fp32 -> bf16 casts
#define NX 1572864           // x  float4 count
#define NWA 442368           // Wa float4 count
#define NWP 147456           // Wp float4 count
__global__ void cvt_all(const float* __restrict__ x, const float* __restrict__ Wa,
                        const float* __restrict__ Wp, bf16_t* __restrict__ xb,
                        bf16_t* __restrict__ Wab, bf16_t* __restrict__ Wpb) {
    int i = blockIdx.x * blockDim.x + threadIdx.x;
    const float4* src; bf16_t* dst; int j;
    if (i < NX)            { src = (const float4*)x;  dst = xb;  j = i; }
    else if (i < NX + NWA) { src = (const float4*)Wa; dst = Wab; j = i - NX; }
    else                   { src = (const float4*)Wp; dst = Wpb; j = i - NX - NWA; }
    float4 f = src[j];
    bf16x4 o = { (bf16_t)f.x, (bf16_t)f.y, (bf16_t)f.z, (bf16_t)f.w };
    ((bf16x4*)dst)[j] = o;
}

// ---------------------------------------------------------------- GEMM main loop
template <int KDIM>
__device__ __forceinline__ void gemm_mainloop(
    const bf16_t* __restrict__ A, const bf16_t* __restrict__ Bt,
    bf16_t* As, bf16_t* Bs, int m0, int n0, int wave, int lane, f32x4 acc[4][4])
{
    const int quad = lane >> 4, l15 = lane & 15;
    const int wm = ((wave >> 1) << 6), wn = ((wave & 1) << 6);

    const int srow = (wave << 4) + (lane >> 2);                 // 0..63
    const int sw   = (((lane & 3) ^ ((srow >> 1) & 3)) << 3);   // swizzled elem offset
    const bf16_t* gA = A  + (size_t)(m0 + srow) * KDIM + sw;
    const bf16_t* gB = Bt + (size_t)(n0 + srow) * KDIM + sw;
    bf16_t* lA0 = As + wave * 512;
    bf16_t* lA1 = As + 2048 + wave * 512;
    bf16_t* lB0 = Bs + wave * 512;
    bf16_t* lB1 = Bs + 2048 + wave * 512;

    const int xorv = ((quad ^ ((l15 >> 1) & 3)) << 3);

    for (int k0 = 0; k0 < KDIM; k0 += 32) {
        __syncthreads();
        gload_lds16(gA + k0,                       lA0);
        gload_lds16(gA + (size_t)64 * KDIM + k0,   lA1);
        gload_lds16(gB + k0,                       lB0);
        gload_lds16(gB + (size_t)64 * KDIM + k0,   lB1);
        __syncthreads();

        bf16x8 af[4], bfr[4];
#pragma unroll
        for (int t = 0; t < 4; t++) {
            af[t]  = *(const bf16x8*)(As + (wm + t * 16 + l15) * 32 + xorv);
            bfr[t] = *(const bf16x8*)(Bs + (wn + t * 16 + l15) * 32 + xorv);
        }
#pragma unroll
        for (int mt = 0; mt < 4; mt++)
#pragma unroll
            for (int nt = 0; nt < 4; nt++)
                acc[mt][nt] = MFMA_BF16_K32(af[mt], bfr[nt], acc[mt][nt]);
    }
}

// ---------------------------------------------------------------- QKV projection
__global__ __launch_bounds__(256) void gemm_qkv(
    const bf16_t* __restrict__ A,   // [8192,768]
    const bf16_t* __restrict__ Bt,  // [2304,768]
    const float* __restrict__ bias, // [2304]
    bf16_t* __restrict__ qo, bf16_t* __restrict__ ko, f16_t* __restrict__ vo)
{
    __shared__ bf16_t As[128 * 32];
    __shared__ bf16_t Bs[128 * 32];
    const int tid = threadIdx.x, wave = tid >> 6, lane = tid & 63;
    const int quad = lane >> 4, l15 = lane & 15;
    const int m0 = blockIdx.y * 128, n0 = blockIdx.x * 128;
    f32x4 acc[4][4] = {};
    gemm_mainloop<768>(A, Bt, As, Bs, m0, n0, wave, lane, acc);

    const int wm = ((wave >> 1) << 6), wn = ((wave & 1) << 6);
#pragma unroll
    for (int nt = 0; nt < 4; nt++) {
        const int cc = n0 + wn + nt * 16 + l15;     // 0..2303
        const float bia = bias[cc];
        const int which = cc / 768;
        const int rem = cc - which * 768;
        const int h = rem >> 6, d = rem & 63;
        if (which < 2) {
            bf16_t* dst = (which == 0) ? qo : ko;
#pragma unroll
            for (int mt = 0; mt < 4; mt++) {
#pragma unroll
                for (int r = 0; r < 4; r++) {
                    const int row = m0 + wm + mt * 16 + quad * 4 + r; // 0..8191
                    const int b = row >> 12, t = row & 4095;
                    dst[((size_t)(b * 12 + h) * 4096 + t) * 64 + d] =
                        (bf16_t)(acc[mt][nt][r] + bia);
                }
            }
        } else {
            // V transposed f16: vo[((b*12+h)*64 + d)*4096 + t]
#pragma unroll
            for (int mt = 0; mt < 4; mt++) {
                const int row0 = m0 + wm + mt * 16 + quad * 4;
                const int b = row0 >> 12, t0 = row0 & 4095;
                f16x4 ov = { (f16_t)(acc[mt][nt][0] + bia),
                             (f16_t)(acc[mt][nt][1] + bia),
                             (f16_t)(acc[mt][nt][2] + bia),
                             (f16_t)(acc[mt][nt][3] + bia) };
                *(f16x4*)(vo + ((size_t)(b * 12 + h) * 64 + d) * 4096 + t0) = ov;
            }
        }
    }
}

// ---------------------------------------------------------------- output projection
__global__ __launch_bounds__(256) void gemm_proj(
    const bf16_t* __restrict__ A,   // y bf16 [8192,768]
    const bf16_t* __restrict__ Bt,  // W_proj bf16 [768,768]
    const float* __restrict__ bias, // [768]
    float* __restrict__ out)        // [8192,768] fp32
{
    __shared__ bf16_t As[128 * 32];
    __shared__ bf16_t Bs[128 * 32];
    const int tid = threadIdx.x, wave = tid >> 6, lane = tid & 63;
    const int quad = lane >> 4, l15 = lane & 15;
    const int m0 = blockIdx.y * 128, n0 = blockIdx.x * 128;
    f32x4 acc[4][4] = {};
    gemm_mainloop<768>(A, Bt, As, Bs, m0, n0, wave, lane, acc);

    const int wm = ((wave >> 1) << 6), wn = ((wave & 1) << 6);
#pragma unroll
    for (int nt = 0; nt < 4; nt++) {
        const int cc = n0 + wn + nt * 16 + l15;
        const float bia = bias[cc];
#pragma unroll
        for (int mt = 0; mt < 4; mt++) {
#pragma unroll
            for (int r = 0; r < 4; r++) {
                const int row = m0 + wm + mt * 16 + quad * 4 + r;
                out[(size_t)row * 768 + cc] = acc[mt][nt][r] + bia;
            }
        }
    }
}

// ---------------------------------------------------------------- flash attention v11
// r7 skeleton + VALU diet, with the r10 spill bug fixed: launch_bounds back to
// (256,3) — r10's (256,4) capped VGPRs at 64 and spilled the O accumulators
// to scratch (927MB WRITE_SIZE). 36.6KB LDS limits blocks/CU to 3-4 anyway.
#define QSCALE 0.1803368801f   // log2(e)/8
__global__ __launch_bounds__(256, 3) void attn_fwd(
    const bf16_t* __restrict__ qg, const bf16_t* __restrict__ kg,
    const f16_t* __restrict__ vtg, bf16_t* __restrict__ y) // y [B,T,C] bf16
{
    __shared__ __align__(16) char smem[36608];
    bf16_t* Ks0 = (bf16_t*)(smem);              // 8KB [key][dim] swizzled
    bf16_t* Ks1 = (bf16_t*)(smem + 8192);
    f16_t*  Vt0 = (f16_t*)(smem + 16384);       // 8KB [dim][key] swizzled
    f16_t*  Vt1 = (f16_t*)(smem + 24576);
    float*  RedA = (float*)(smem);              // epilogue overlays (stride 68)
    float*  RedB = (float*)(smem + 17408);
    float*  Psr  = (float*)(smem + 34816);      // [4][64]
    float*  PsT  = (float*)(smem + 35840);      // [64]

    const int tid = threadIdx.x, wave = tid >> 6, lane = tid & 63;
    const int quad = lane >> 4, l15 = lane & 15;

    const int blk = blockIdx.x;            // 0..1535
    const int xcd = blk & 7;
    const int idx = blk >> 3;              // 0..191
    const int hl  = idx % 3;
    const int qt  = idx / 3;               // 0..63
    const int bh  = xcd * 3 + hl;          // 0..23
    const int b = bh / 12, h = bh - b * 12;
    const size_t base = (size_t)bh * 4096 * 64;

    // Q fragments for all 4 qrow-chunks (B-operand: n=l15, k=quad*8+j), *log2e/8
    bf16x8 qf[4][2];
#pragma unroll
    for (int qc = 0; qc < 4; qc++) {
        const int qrow = qt * 64 + qc * 16 + l15;
        qf[qc][0] = *(const bf16x8*)(qg + base + (size_t)qrow * 64 + quad * 8);
        qf[qc][1] = *(const bf16x8*)(qg + base + (size_t)qrow * 64 + 32 + quad * 8);
#pragma unroll
        for (int j = 0; j < 8; j++) {
            qf[qc][0][j] = (bf16_t)((float)qf[qc][0][j] * QSCALE);
            qf[qc][1][j] = (bf16_t)((float)qf[qc][1][j] * QSCALE);
        }
    }

    f32x4 O[4][4] = {};      // O^T partial: [dt][qc]; dim=dt*16+quad*4+r, qrow=qc*16+l15
    float psum[4] = {};      // per-lane partial row sums (qrow = qc*16+l15)
    const f16x2 one2 = { (f16_t)1.0f, (f16_t)1.0f };

    // staging: 8 lanes per 128B row, 16B chunks XOR-swizzled on row&7
    const int srow8 = tid >> 3;                  // 0..31 (+32 for i=1)
    const int sc8   = (tid & 7) ^ (srow8 & 7);
    const int l8 = l15 & 7;
    const int w16 = wave << 4;
    const int ksoff = (quad ^ l8) << 3;                          // K frag slot (elems)
    const int vslot = ((wave << 1) | (quad >> 1)) ^ l8;          // V frag 16B slot
    const int q0off = (quad & 1) * 8;

    auto stage = [&](const bf16_t* kp, const f16_t* vp, bf16_t* Kd, f16_t* Vd) {
#pragma unroll
        for (int i = 0; i < 2; i++) {
            gload_lds16(kp + (i * 32 + srow8) * 64 + sc8 * 8,           Kd + (i * 256 + tid) * 8);
            gload_lds16(vp + (size_t)(i * 32 + srow8) * 4096 + sc8 * 8, Vd + (i * 256 + tid) * 8);
        }
    };

    auto compute = [&](const bf16_t* ks, const f16_t* vs) {
        // ---- S^T (wave's 16 keys x 64 qrows): 2 LDS reads feed 8 MFMAs
        const bf16_t* kr = ks + (w16 + l15) * 64;
        bf16x8 kf0 = *(const bf16x8*)(kr + ksoff);
        bf16x8 kf1 = *(const bf16x8*)(kr + (ksoff ^ 32));
        f32x4 sc[4];
#pragma unroll
        for (int qc = 0; qc < 4; qc++) {
            f32x4 s = {};
            s = MFMA_BF16_K32(kf0, qf[qc][0], s);
            s = MFMA_BF16_K32(kf1, qf[qc][1], s);
            sc[qc] = s;
        }
        // ---- P = exp2(S^T): bare v_exp_f32 + packed f16 cvt + dot2 row-sums
        f16x4 pf[4];
#pragma unroll
        for (int qc = 0; qc < 4; qc++) {
            float e0 = __builtin_amdgcn_exp2f(sc[qc][0]);
            float e1 = __builtin_amdgcn_exp2f(sc[qc][1]);
            float e2 = __builtin_amdgcn_exp2f(sc[qc][2]);
            float e3 = __builtin_amdgcn_exp2f(sc[qc][3]);
            f16x2 lo = pkrtz(e0, e1);
            f16x2 hi = pkrtz(e2, e3);
            psum[qc] = __builtin_amdgcn_fdot2(lo, one2, psum[qc], false);
            psum[qc] = __builtin_amdgcn_fdot2(hi, one2, psum[qc], false);
            f16x4 p;
            *(f16x2*)&p = lo;
            *(((f16x2*)&p) + 1) = hi;
            pf[qc] = p;
        }
        // ---- O^T += V^T P : 4 LDS b64 reads feed 16 MFMAs
#pragma unroll
        for (int dt = 0; dt < 4; dt++) {
            const char* vr = (const char*)(vs + (dt * 16 + l15) * 64);
            f16x4 vf = *(const f16x4*)(vr + vslot * 16 + q0off);
#pragma unroll
            for (int qc = 0; qc < 4; qc++)
                O[dt][qc] = MFMA_F16_K16(vf, pf[qc], O[dt][qc]);
        }
    };

    const bf16_t* kp = kg + base;    // +4096 elems (8KB) per 64-key tile
    const f16_t*  vp = vtg + base;   // +64 elems per tile
    stage(kp, vp, Ks0, Vt0); kp += 4096; vp += 64;
    for (int kt = 0; kt < 64; kt += 2) {
        __syncthreads();                 // buf0 loads drained; buf1 readers done
        stage(kp, vp, Ks1, Vt1); kp += 4096; vp += 64;
        compute(Ks0, Vt0);
        __syncthreads();
        if (kt + 2 < 64) { stage(kp, vp, Ks0, Vt0); kp += 4096; vp += 64; }
        compute(Ks1, Vt1);
    }

    // ================= epilogue: reduce O & psum across the 4 key-split waves
#pragma unroll
    for (int qc = 0; qc < 4; qc++) {
        psum[qc] += __shfl_xor(psum[qc], 16, 64);
        psum[qc] += __shfl_xor(psum[qc], 32, 64);
    }
    __syncthreads();   // K-loop LDS quiesced; overlay safe
    if (wave == 2) {
#pragma unroll
        for (int dt = 0; dt < 4; dt++)
#pragma unroll
            for (int qc = 0; qc < 4; qc++)
                *(f32x4*)(RedA + (qc * 16 + l15) * 68 + dt * 16 + quad * 4) = O[dt][qc];
    } else if (wave == 3) {
#pragma unroll
        for (int dt = 0; dt < 4; dt++)
#pragma unroll
            for (int qc = 0; qc < 4; qc++)
                *(f32x4*)(RedB + (qc * 16 + l15) * 68 + dt * 16 + quad * 4) = O[dt][qc];
    }
    if (quad == 0) {
#pragma unroll
        for (int qc = 0; qc < 4; qc++) Psr[wave * 64 + qc * 16 + l15] = psum[qc];
    }
    __syncthreads();   // S2
    if (wave == 0) {
#pragma unroll
        for (int dt = 0; dt < 4; dt++)
#pragma unroll
            for (int qc = 0; qc < 4; qc++)
                O[dt][qc] += *(const f32x4*)(RedA + (qc * 16 + l15) * 68 + dt * 16 + quad * 4);
    } else if (wave == 1) {
#pragma unroll
        for (int dt = 0; dt < 4; dt++)
#pragma unroll
            for (int qc = 0; qc < 4; qc++)
                O[dt][qc] += *(const f32x4*)(RedB + (qc * 16 + l15) * 68 + dt * 16 + quad * 4);
    }
    __syncthreads();   // S3
    if (wave == 1) {
#pragma unroll
        for (int dt = 0; dt < 4; dt++)
#pragma unroll
            for (int qc = 0; qc < 4; qc++)
                *(f32x4*)(RedA + (qc * 16 + l15) * 68 + dt * 16 + quad * 4) = O[dt][qc];
    } else if (wave == 3) {
        PsT[lane] = Psr[lane] + Psr[64 + lane] + Psr[128 + lane] + Psr[192 + lane];
    }
    __syncthreads();   // S4
    if (wave == 0) {
#pragma unroll
        for (int qc = 0; qc < 4; qc++) {
            const float rcp = 1.0f / PsT[qc * 16 + l15];
            const int t = qt * 64 + qc * 16 + l15;
            bf16_t* yr = y + ((size_t)b * 4096 + t) * 768 + h * 64 + quad * 4;
#pragma unroll
            for (int dt = 0; dt < 4; dt++) {
                f32x4 o4 = O[dt][qc] +
                    *(const f32x4*)(RedA + (qc * 16 + l15) * 68 + dt * 16 + quad * 4);
                bf16x4 ov = { (bf16_t)(o4[0] * rcp), (bf16_t)(o4[1] * rcp),
                              (bf16_t)(o4[2] * rcp), (bf16_t)(o4[3] * rcp) };
                *(bf16x4*)(yr + dt * 16) = ov;
            }
        }
    }
}

// ---------------------------------------------------------------- launch
extern "C" void kernel_launch(void* const* d_in, const int* in_sizes, int n_in,
                              void* d_out, int out_size, void* d_ws, size_t ws_size,
                              hipStream_t stream) {
    const float* x  = (const float*)d_in[0]; // [2,4096,768]
    const float* Wa = (const float*)d_in[1]; // [2304,768]
    const float* ba = (const float*)d_in[2]; // [2304]
    const float* Wp = (const float*)d_in[3]; // [768,768]
    const float* bp = (const float*)d_in[4]; // [768]
    float* out = (float*)d_out;              // [2,4096,768]

    char* ws = (char*)d_ws;
    bf16_t* xb  = (bf16_t*)(ws);                 //  6291456 elts
    bf16_t* Wab = (bf16_t*)(ws + 12582912);      //  1769472
    bf16_t* Wpb = (bf16_t*)(ws + 16121856);      //   589824
    bf16_t* qb  = (bf16_t*)(ws + 17301504);      //  [B,H,T,D] bf16
    bf16_t* kb  = (bf16_t*)(ws + 29884416);      //  [B,H,T,D] bf16
    f16_t*  vtb = (f16_t*)(ws + 42467328);       //  [B,H,D,T] f16 (transposed)
    bf16_t* yb  = (bf16_t*)(ws + 55050240);      //  [B,T,C] bf16

    cvt_all<<<8448, 256, 0, stream>>>(x, Wa, Wp, xb, Wab, Wpb);
    gemm_qkv <<<dim3(18, 64), 256, 0, stream>>>(xb, Wab, ba, qb, kb, vtb);
    attn_fwd <<<1536, 256, 0, stream>>>(qb, kb, vtb, yb);
    gemm_proj<<<dim3( 6, 64), 256, 0, stream>>>(yb, Wpb, bp, out);
}